// Round 9
// baseline (177.170 us; speedup 1.0000x reference)
//
#include <hip/hip_runtime.h>
#include <hip/hip_bf16.h>
#include <hip/hip_cooperative_groups.h>

namespace cg = cooperative_groups;

using bf16 = __hip_bfloat16;
typedef __attribute__((ext_vector_type(8))) short short8;   // 8 bf16 = 4 VGPRs
typedef __attribute__((ext_vector_type(4))) float floatx4;  // 4 fp32 acc
typedef __attribute__((ext_vector_type(8))) int int8v;      // 32 fp8 = 8 VGPRs

__device__ __forceinline__ void async_ld16(const void* g, void* l) {
  __builtin_amdgcn_global_load_lds((const __attribute__((address_space(1))) void*)g,
                                   (__attribute__((address_space(3))) void*)l, 16, 0, 0);
}

__device__ __forceinline__ int pk4_fp8(float a, float b, float c, float d) {
  int v = __builtin_amdgcn_cvt_pk_fp8_f32(a, b, 0, false);
  return __builtin_amdgcn_cvt_pk_fp8_f32(c, d, v, true);  // bytes [a,b,c,d]
}

__device__ __forceinline__ int8v ld_frag16(const unsigned char* lo, const unsigned char* hi) {
  int4 l0 = *(const int4*)lo, h0 = *(const int4*)hi;
  int8v v;
  v[0] = l0.x; v[1] = l0.y; v[2] = l0.z; v[3] = l0.w;
  v[4] = h0.x; v[5] = h0.y; v[6] = h0.z; v[7] = h0.w;
  return v;
}

// ---------------- bf16 128x128 tile core (BK=64), XOR-swizzled LDS (32KB) ----------
__device__ __forceinline__ void gemm_core(const bf16* __restrict__ At,
                                          const bf16* __restrict__ Bt,
                                          int K, bf16* lA, bf16* lB,
                                          floatx4 acc[4][4]) {
  const int tid  = threadIdx.x;
  const int w    = tid >> 6;
  const int lane = tid & 63;
  const int subM = (w >> 1) * 64;
  const int subN = (w & 1) * 64;
  const int fr   = lane & 15;
  const int fq   = lane >> 4;

  int srow[4], scol[4], sdst[4];
#pragma unroll
  for (int q = 0; q < 4; ++q) {
    int p = q * 256 + w * 64 + lane;
    int r = p >> 3;
    int j = (p & 7) ^ (r & 7);
    srow[q] = r;
    scol[q] = j * 8;
    sdst[q] = (q * 256 + w * 64) * 8;
  }
  int offA[2][4], offB[2][4];
#pragma unroll
  for (int kc = 0; kc < 2; ++kc)
#pragma unroll
    for (int i = 0; i < 4; ++i) {
      int rA = subM + i * 16 + fr;
      offA[kc][i] = (rA * 8 + ((kc * 4 + fq) ^ (rA & 7))) * 8;
      int rB = subN + i * 16 + fr;
      offB[kc][i] = (rB * 8 + ((kc * 4 + fq) ^ (rB & 7))) * 8;
    }

  floatx4 zero = {0.f, 0.f, 0.f, 0.f};
#pragma unroll
  for (int i = 0; i < 4; ++i)
#pragma unroll
    for (int j = 0; j < 4; ++j) acc[i][j] = zero;

  for (int k0 = 0; k0 < K; k0 += 64) {
    __syncthreads();
#pragma unroll
    for (int q = 0; q < 4; ++q) {
      async_ld16(At + (size_t)srow[q] * K + k0 + scol[q], lA + sdst[q]);
      async_ld16(Bt + (size_t)srow[q] * K + k0 + scol[q], lB + sdst[q]);
    }
    __syncthreads();
#pragma unroll
    for (int kc = 0; kc < 2; ++kc) {
      short8 a[4], b[4];
#pragma unroll
      for (int i = 0; i < 4; ++i) a[i] = *(const short8*)(lA + offA[kc][i]);
#pragma unroll
      for (int j = 0; j < 4; ++j) b[j] = *(const short8*)(lB + offB[kc][j]);
#pragma unroll
      for (int i = 0; i < 4; ++i)
#pragma unroll
        for (int j = 0; j < 4; ++j)
          acc[i][j] = __builtin_amdgcn_mfma_f32_16x16x32_bf16(a[i], b[j], acc[i][j], 0, 0, 0);
    }
  }
}

// ---------------- fp8 128x128 tile core (BK=128), improved swizzle (32KB) ----------
__device__ __forceinline__ void gemm_core_f8(const unsigned char* __restrict__ At,
                                             const unsigned char* __restrict__ Bt,
                                             int K, unsigned char* lA, unsigned char* lB,
                                             floatx4 acc[4][4]) {
  const int tid  = threadIdx.x;
  const int w    = tid >> 6;
  const int lane = tid & 63;
  const int subM = (w >> 1) * 64;
  const int subN = (w & 1) * 64;
  const int fr   = lane & 15;
  const int fq   = lane >> 4;

  int srow[4], scol[4], sdst[4];
#pragma unroll
  for (int q = 0; q < 4; ++q) {
    int p = q * 256 + w * 64 + lane;
    int r = p >> 3;
    int j = (p & 7) ^ (r & 7) ^ ((r & 8) >> 1);
    srow[q] = r;
    scol[q] = j * 16;
    sdst[q] = (q * 256 + w * 64) * 16;
  }
  int offA[2][4], offB[2][4];
#pragma unroll
  for (int h = 0; h < 2; ++h)
#pragma unroll
    for (int i = 0; i < 4; ++i) {
      int rA = subM + i * 16 + fr;
      offA[h][i] = rA * 128 + (((fq * 2 + h) ^ (rA & 7) ^ ((rA & 8) >> 1)) * 16);
      int rB = subN + i * 16 + fr;
      offB[h][i] = rB * 128 + (((fq * 2 + h) ^ (rB & 7) ^ ((rB & 8) >> 1)) * 16);
    }

  floatx4 zero = {0.f, 0.f, 0.f, 0.f};
#pragma unroll
  for (int i = 0; i < 4; ++i)
#pragma unroll
    for (int j = 0; j < 4; ++j) acc[i][j] = zero;

  for (int k0 = 0; k0 < K; k0 += 128) {
    __syncthreads();
#pragma unroll
    for (int q = 0; q < 4; ++q) {
      async_ld16(At + (size_t)srow[q] * K + k0 + scol[q], lA + sdst[q]);
      async_ld16(Bt + (size_t)srow[q] * K + k0 + scol[q], lB + sdst[q]);
    }
    __syncthreads();
    int8v a[4], b[4];
#pragma unroll
    for (int i = 0; i < 4; ++i) a[i] = ld_frag16(lA + offA[0][i], lA + offA[1][i]);
#pragma unroll
    for (int j = 0; j < 4; ++j) b[j] = ld_frag16(lB + offB[0][j], lB + offB[1][j]);
#pragma unroll
    for (int i = 0; i < 4; ++i)
#pragma unroll
      for (int j = 0; j < 4; ++j)
        acc[i][j] = __builtin_amdgcn_mfma_scale_f32_16x16x128_f8f6f4(
            a[i], b[j], acc[i][j], 0, 0, 0, 0x7F7F7F7F, 0, 0x7F7F7F7F);
  }
}

// ------------- fp8 v2 core: block 128x256, wave tile 64x128, BK=128 (48KB) ---------
// (fallback path only — 48KB LDS blocks the cooperative launch)
__device__ __forceinline__ void gemm_core_f8_v2(const unsigned char* __restrict__ At,
                                                const unsigned char* __restrict__ Bt,
                                                int K, unsigned char* lA, unsigned char* lB,
                                                floatx4 acc[4][8]) {
  const int tid  = threadIdx.x;
  const int w    = tid >> 6;
  const int lane = tid & 63;
  const int subM = (w >> 1) * 64;
  const int subN = (w & 1) * 128;
  const int fr   = lane & 15;
  const int fq   = lane >> 4;

  int srowA[4], scolA[4], sdstA[4];
#pragma unroll
  for (int q = 0; q < 4; ++q) {
    int p = q * 256 + w * 64 + lane;
    int r = p >> 3;
    int j = (p & 7) ^ (r & 7) ^ ((r & 8) >> 1);
    srowA[q] = r; scolA[q] = j * 16; sdstA[q] = (q * 256 + w * 64) * 16;
  }
  int srowB[8], scolB[8], sdstB[8];
#pragma unroll
  for (int q = 0; q < 8; ++q) {
    int p = q * 256 + w * 64 + lane;
    int r = p >> 3;
    int j = (p & 7) ^ (r & 7) ^ ((r & 8) >> 1);
    srowB[q] = r; scolB[q] = j * 16; sdstB[q] = (q * 256 + w * 64) * 16;
  }
  int offA[2][4], offB[2][8];
#pragma unroll
  for (int h = 0; h < 2; ++h) {
#pragma unroll
    for (int i = 0; i < 4; ++i) {
      int rA = subM + i * 16 + fr;
      offA[h][i] = rA * 128 + (((fq * 2 + h) ^ (rA & 7) ^ ((rA & 8) >> 1)) * 16);
    }
#pragma unroll
    for (int j = 0; j < 8; ++j) {
      int rB = subN + j * 16 + fr;
      offB[h][j] = rB * 128 + (((fq * 2 + h) ^ (rB & 7) ^ ((rB & 8) >> 1)) * 16);
    }
  }

  floatx4 zero = {0.f, 0.f, 0.f, 0.f};
#pragma unroll
  for (int i = 0; i < 4; ++i)
#pragma unroll
    for (int j = 0; j < 8; ++j) acc[i][j] = zero;

  for (int k0 = 0; k0 < K; k0 += 128) {
    __syncthreads();
#pragma unroll
    for (int q = 0; q < 4; ++q)
      async_ld16(At + (size_t)srowA[q] * K + k0 + scolA[q], lA + sdstA[q]);
#pragma unroll
    for (int q = 0; q < 8; ++q)
      async_ld16(Bt + (size_t)srowB[q] * K + k0 + scolB[q], lB + sdstB[q]);
    __syncthreads();
    int8v a[4];
#pragma unroll
    for (int i = 0; i < 4; ++i) a[i] = ld_frag16(lA + offA[0][i], lA + offA[1][i]);
#pragma unroll
    for (int j = 0; j < 8; ++j) {
      int8v bf = ld_frag16(lB + offB[0][j], lB + offB[1][j]);
#pragma unroll
      for (int i = 0; i < 4; ++i)
        acc[i][j] = __builtin_amdgcn_mfma_scale_f32_16x16x128_f8f6f4(
            a[i], bf, acc[i][j], 0, 0, 0, 0x7F7F7F7F, 0, 0x7F7F7F7F);
    }
  }
}

// ===================== cooperative kernel: 4 phases, 32KB LDS ======================
__global__ __launch_bounds__(256, 2) void fused_all(
    const float* __restrict__ x, const float* __restrict__ wq,
    const float* __restrict__ wk, const float* __restrict__ wv,
    bf16* __restrict__ Xbf, unsigned char* __restrict__ X8,
    unsigned char* __restrict__ Wq8, unsigned char* __restrict__ Wk8,
    bf16* __restrict__ Wvbf, bf16* __restrict__ Vbf,
    unsigned char* __restrict__ Qf8, unsigned char* __restrict__ Kf8,
    unsigned char* __restrict__ S8, unsigned char* __restrict__ Vt8,
    float* __restrict__ l, float* __restrict__ out) {
  __shared__ __align__(16) char lds[32768];
  cg::grid_group grid = cg::this_grid();
  const int rb = blockIdx.x;   // [0,512)
  const int t = threadIdx.x;
  const int w = t >> 6, lane = t & 63;
  const int fr = lane & 15, fq = lane >> 4;

  // ---------------- phase 0: casts ----------------
  for (int blk = rb; blk < 11272; blk += 512) {
    if (blk < 8192) {
      int i = blk * 256 + t;
      float4 f = ((const float4*)x)[i];
      bf16 tmp[4] = {__float2bfloat16(f.x), __float2bfloat16(f.y),
                     __float2bfloat16(f.z), __float2bfloat16(f.w)};
      ((ushort4*)Xbf)[i] = *(const ushort4*)tmp;
      ((unsigned int*)X8)[i] = (unsigned int)pk4_fp8(f.x, f.y, f.z, f.w);
    } else if (blk < 10240) {
      const float* src = (blk < 9216) ? wq : wk;
      unsigned char* dst = (blk < 9216) ? Wq8 : Wk8;
      int i = ((blk - 8192) & 1023) * 256 + t;
      float4 f = ((const float4*)src)[i];
      ((unsigned int*)dst)[i] = (unsigned int)pk4_fp8(f.x, f.y, f.z, f.w);
    } else if (blk < 11264) {
      int i = (blk - 10240) * 256 + t;
      float4 f = ((const float4*)wv)[i];
      bf16 tmp[4] = {__float2bfloat16(f.x), __float2bfloat16(f.y),
                     __float2bfloat16(f.z), __float2bfloat16(f.w)};
      ((ushort4*)Wvbf)[i] = *(const ushort4*)tmp;
    } else {
      int i = (blk - 11264) * 256 + t;
      ((float4*)l)[i] = make_float4(0.f, 0.f, 0.f, 0.f);
    }
  }
  __threadfence();
  grid.sync();

  // ---------------- phase 1: V proj (bf16) + Q proj + K proj (fp8 v1) ----------
  {  // V projection
    const int r = rb & 7, g = rb >> 3;
    const int ty = r * 8 + (g & 7), tx = g >> 3;
    floatx4 acc[4][4];
    gemm_core(Xbf + (size_t)ty * 128 * 1024, Wvbf + (size_t)tx * 128 * 1024,
              1024, (bf16*)lds, (bf16*)(lds + 16384), acc);
    const int subM = (w >> 1) * 64, subN = (w & 1) * 64;
    const int rowBase = ty * 128 + subM;
    const int colBase = tx * 128 + subN;
#pragma unroll
    for (int i = 0; i < 4; ++i)
#pragma unroll
      for (int j = 0; j < 4; ++j)
#pragma unroll
        for (int rr = 0; rr < 4; ++rr) {
          int row = rowBase + i * 16 + fq * 4 + rr;
          int col = colBase + j * 16 + fr;
          Vbf[(size_t)row * 1024 + col] = __float2bfloat16(acc[i][j][rr]);
        }
  }
#pragma unroll 1
  for (int z = 0; z < 2; ++z) {  // Q/K projection, fp8 v1, pi-permuted (k=d)
    const int r = rb & 7, g = rb >> 3;
    const int ty = r * 8 + (g & 7), tx = g >> 3;
    floatx4 acc[4][4];
    gemm_core_f8(X8 + (size_t)ty * 128 * 1024,
                 (z == 0 ? Wq8 : Wk8) + (size_t)tx * 128 * 1024, 1024,
                 (unsigned char*)lds, (unsigned char*)(lds + 16384), acc);
    unsigned char* dst = (z == 0) ? Qf8 : Kf8;
    const int subM = (w >> 1) * 64, subN = (w & 1) * 64;
    const int rowBase = ty * 128 + subM;
    const int colBase = tx * 128 + subN;
#pragma unroll
    for (int i = 0; i < 4; ++i)
#pragma unroll
      for (int rr = 0; rr < 4; ++rr) {
        int row = rowBase + i * 16 + fq * 4 + rr;
        unsigned int p = (unsigned int)pk4_fp8(acc[i][0][rr], acc[i][1][rr],
                                               acc[i][2][rr], acc[i][3][rr]);
        *(unsigned int*)&dst[(size_t)row * 1024 + colBase + fr * 4] = p;
      }
  }
  __threadfence();
  grid.sync();

  // ---------------- phase 2: QK^T+exp (2 tiles, fp8 v1) + V transpose (4 tiles) ----
#pragma unroll 1
  for (int q = 0; q < 2; ++q) {
    const int id = rb + q * 512;
    const int r = id & 7, g = id >> 3;
    const int b = g >> 5;
    const int rem = g & 31;
    const int ty = r * 2 + (rem & 1);
    const int tx = rem >> 1;
    floatx4 acc[4][4];
    gemm_core_f8(Qf8 + (size_t)b * 2048 * 1024 + (size_t)ty * 128 * 1024,
                 Kf8 + (size_t)b * 2048 * 1024 + (size_t)tx * 128 * 1024, 1024,
                 (unsigned char*)lds, (unsigned char*)(lds + 16384), acc);
    const int subM = (w >> 1) * 64, subN = (w & 1) * 64;
    const int rowBase = ty * 128 + subM;
    const int colBase = tx * 128 + subN;
    unsigned char* Sb = S8 + (size_t)b * 2048 * 2048;
    float* lb = l + (size_t)b * 2048;
#pragma unroll
    for (int i = 0; i < 4; ++i)
#pragma unroll
      for (int rr = 0; rr < 4; ++rr) {
        int row = rowBase + i * 16 + fq * 4 + rr;
        unsigned int p = (unsigned int)pk4_fp8(
            __expf(acc[i][0][rr] * 0.03125f), __expf(acc[i][1][rr] * 0.03125f),
            __expf(acc[i][2][rr] * 0.03125f), __expf(acc[i][3][rr] * 0.03125f));
        *(unsigned int*)&Sb[(size_t)row * 2048 + colBase + fr * 4] = p;
        float psum = __builtin_amdgcn_cvt_f32_fp8(p, 0) + __builtin_amdgcn_cvt_f32_fp8(p, 1) +
                     __builtin_amdgcn_cvt_f32_fp8(p, 2) + __builtin_amdgcn_cvt_f32_fp8(p, 3);
        psum += __shfl_xor(psum, 1, 64);
        psum += __shfl_xor(psum, 2, 64);
        psum += __shfl_xor(psum, 4, 64);
        psum += __shfl_xor(psum, 8, 64);
        if (fr == 0) atomicAdd(&lb[row], psum);
      }
  }
#pragma unroll 1
  for (int q = 0; q < 4; ++q) {  // V transpose: Vbf[b][s][v] -> Vt8[b][v][pi(s)]
    const int t2 = rb * 4 + q;
    const int b = t2 >> 9, rem = t2 & 511;
    const int xs = rem & 31, yv = rem >> 5;
    const int s0 = xs * 64, v0 = yv * 64;
    short(*tile)[72] = (short(*)[72])lds;
    __syncthreads();
#pragma unroll
    for (int i = 0; i < 2; ++i) {
      int c = t + i * 256;
      int row = c >> 3, cj = c & 7;
      *(short8*)&tile[row][cj * 8] =
          *(const short8*)&Vbf[((size_t)(b * 2048 + s0 + row)) * 1024 + v0 + cj * 8];
    }
    __syncthreads();
    const int vrow = t >> 2, sq = t & 3;
#pragma unroll
    for (int hc = 0; hc < 2; ++hc) {
      float f[8];
#pragma unroll
      for (int e = 0; e < 8; ++e) {
        int p = sq * 16 + hc * 8 + e;
        int s = (p & 3) * 16 + (p >> 2);    // inverse-pi
        short sh = tile[s][vrow];
        f[e] = __bfloat162float(*(bf16*)&sh);
      }
      uint2 packed;
      packed.x = (unsigned int)pk4_fp8(f[0], f[1], f[2], f[3]);
      packed.y = (unsigned int)pk4_fp8(f[4], f[5], f[6], f[7]);
      *(uint2*)&Vt8[((size_t)(b * 1024 + v0 + vrow)) * 2048 + s0 + sq * 16 + hc * 8] = packed;
    }
  }
  __threadfence();
  grid.sync();

  // ---------------- phase 3: PV + normalize + residual -----------------------------
  {
    const int r = rb & 7, g = rb >> 3;
    const int b = g >> 4;
    const int rem = g & 15;
    const int ty = r * 2 + (rem & 1);
    const int tx = rem >> 1;
    floatx4 acc[4][4];
    gemm_core_f8(S8 + (size_t)b * 2048 * 2048 + (size_t)ty * 128 * 2048,
                 Vt8 + (size_t)b * 1024 * 2048 + (size_t)tx * 128 * 2048, 2048,
                 (unsigned char*)lds, (unsigned char*)(lds + 16384), acc);
    const int subM = (w >> 1) * 64, subN = (w & 1) * 64;
    const int rowBase = ty * 128 + subM;
    const int colBase = tx * 128 + subN;
    const float* lb = l + (size_t)b * 2048;
#pragma unroll
    for (int i = 0; i < 4; ++i)
#pragma unroll
      for (int rr = 0; rr < 4; ++rr) {
        int row = rowBase + i * 16 + fq * 4 + rr;
        float inv = 1.0f / lb[row];
#pragma unroll
        for (int j = 0; j < 4; ++j) {
          int col = colBase + j * 16 + fr;
          size_t oi = ((size_t)b * 2048 + row) * 1024 + col;
          out[oi] = acc[i][j][rr] * inv + __bfloat162float(Vbf[oi]);
        }
      }
  }
}

// ===================== fallback path: R7's 4 kernels (verbatim) ====================
__global__ __launch_bounds__(256, 2) void proj_gemm(
    const bf16* __restrict__ Xbf, const bf16* __restrict__ Wvbf, bf16* __restrict__ Vbf,
    const unsigned char* __restrict__ X8, const unsigned char* __restrict__ Wq8,
    const unsigned char* __restrict__ Wk8,
    unsigned char* __restrict__ Qf8, unsigned char* __restrict__ Kf8) {
  __shared__ __align__(16) char lds[49152];
  const int id = blockIdx.x;
  const int tid = threadIdx.x, w = tid >> 6, lane = tid & 63;
  const int fr = lane & 15, fq = lane >> 4;

  if (id < 512) {
    const int r = id & 7, g = id >> 3;
    const int ty = r * 8 + (g & 7), tx = g >> 3;
    floatx4 acc[4][4];
    gemm_core(Xbf + (size_t)ty * 128 * 1024, Wvbf + (size_t)tx * 128 * 1024,
              1024, (bf16*)lds, (bf16*)(lds + 16384), acc);
    const int subM = (w >> 1) * 64, subN = (w & 1) * 64;
    const int rowBase = ty * 128 + subM;
    const int colBase = tx * 128 + subN;
#pragma unroll
    for (int i = 0; i < 4; ++i)
#pragma unroll
      for (int j = 0; j < 4; ++j)
#pragma unroll
        for (int rr = 0; rr < 4; ++rr) {
          int row = rowBase + i * 16 + fq * 4 + rr;
          int col = colBase + j * 16 + fr;
          Vbf[(size_t)row * 1024 + col] = __float2bfloat16(acc[i][j][rr]);
        }
  } else {
    const int local = id - 512;
    const int z = local >> 8, lid = local & 255;
    const int r = lid & 7, g = lid >> 3;
    const int ty = r * 8 + (g & 7);
    const int tx = g >> 3;
    floatx4 acc[4][8];
    gemm_core_f8_v2(X8 + (size_t)ty * 128 * 1024,
                    (z == 0 ? Wq8 : Wk8) + (size_t)tx * 256 * 1024, 1024,
                    (unsigned char*)lds, (unsigned char*)(lds + 16384), acc);
    unsigned char* dst = (z == 0) ? Qf8 : Kf8;
    const int subM = (w >> 1) * 64, subN = (w & 1) * 128;
    const int rowBase = ty * 128 + subM;
    const int colBase = tx * 256 + subN;
#pragma unroll
    for (int i = 0; i < 4; ++i)
#pragma unroll
      for (int rr = 0; rr < 4; ++rr) {
        int row = rowBase + i * 16 + fq * 4 + rr;
        unsigned int p0 = (unsigned int)pk4_fp8(acc[i][0][rr], acc[i][1][rr],
                                                acc[i][2][rr], acc[i][3][rr]);
        unsigned int p1 = (unsigned int)pk4_fp8(acc[i][4][rr], acc[i][5][rr],
                                                acc[i][6][rr], acc[i][7][rr]);
        *(unsigned int*)&dst[(size_t)row * 1024 + colBase + fr * 4] = p0;
        *(unsigned int*)&dst[(size_t)row * 1024 + colBase + 64 + fr * 4] = p1;
      }
  }
}

__global__ __launch_bounds__(256, 2) void mid_kernel(
    const unsigned char* __restrict__ Qf8, const unsigned char* __restrict__ Kf8,
    unsigned char* __restrict__ S8, float* __restrict__ l,
    const bf16* __restrict__ Vbf, unsigned char* __restrict__ Vt8) {
  __shared__ __align__(16) char lds[49152];
  const int id = blockIdx.x;
  const int t = threadIdx.x;

  if (id < 512) {
    const int r = id & 7, g = id >> 3;
    const int b = g >> 4;
    const int rem = g & 15;
    const int ty = r * 2 + (rem & 1);
    const int tx = rem >> 1;
    floatx4 acc[4][8];
    gemm_core_f8_v2(Qf8 + (size_t)b * 2048 * 1024 + (size_t)ty * 128 * 1024,
                    Kf8 + (size_t)b * 2048 * 1024 + (size_t)tx * 256 * 1024, 1024,
                    (unsigned char*)lds, (unsigned char*)(lds + 16384), acc);
    const int w = t >> 6, lane = t & 63;
    const int subM = (w >> 1) * 64, subN = (w & 1) * 128;
    const int fr = lane & 15, fq = lane >> 4;
    const int rowBase = ty * 128 + subM;
    const int colBase = tx * 256 + subN;
    unsigned char* Sb = S8 + (size_t)b * 2048 * 2048;
    float* lb = l + (size_t)b * 2048;
#pragma unroll
    for (int i = 0; i < 4; ++i)
#pragma unroll
      for (int rr = 0; rr < 4; ++rr) {
        int row = rowBase + i * 16 + fq * 4 + rr;
        unsigned int p0 = (unsigned int)pk4_fp8(
            __expf(acc[i][0][rr] * 0.03125f), __expf(acc[i][1][rr] * 0.03125f),
            __expf(acc[i][2][rr] * 0.03125f), __expf(acc[i][3][rr] * 0.03125f));
        unsigned int p1 = (unsigned int)pk4_fp8(
            __expf(acc[i][4][rr] * 0.03125f), __expf(acc[i][5][rr] * 0.03125f),
            __expf(acc[i][6][rr] * 0.03125f), __expf(acc[i][7][rr] * 0.03125f));
        *(unsigned int*)&Sb[(size_t)row * 2048 + colBase + fr * 4] = p0;
        *(unsigned int*)&Sb[(size_t)row * 2048 + colBase + 64 + fr * 4] = p1;
        float psum = __builtin_amdgcn_cvt_f32_fp8(p0, 0) + __builtin_amdgcn_cvt_f32_fp8(p0, 1) +
                     __builtin_amdgcn_cvt_f32_fp8(p0, 2) + __builtin_amdgcn_cvt_f32_fp8(p0, 3) +
                     __builtin_amdgcn_cvt_f32_fp8(p1, 0) + __builtin_amdgcn_cvt_f32_fp8(p1, 1) +
                     __builtin_amdgcn_cvt_f32_fp8(p1, 2) + __builtin_amdgcn_cvt_f32_fp8(p1, 3);
        psum += __shfl_xor(psum, 1, 64);
        psum += __shfl_xor(psum, 2, 64);
        psum += __shfl_xor(psum, 4, 64);
        psum += __shfl_xor(psum, 8, 64);
        if (fr == 0) atomicAdd(&lb[row], psum);
      }
  } else {
    const int t2 = id - 512;
    const int b = t2 >> 9, rem = t2 & 511;
    const int xs = rem & 31, yv = rem >> 5;
    const int s0 = xs * 64, v0 = yv * 64;
    short(*tile)[72] = (short(*)[72])lds;
#pragma unroll
    for (int i = 0; i < 2; ++i) {
      int c = t + i * 256;
      int row = c >> 3, cj = c & 7;
      *(short8*)&tile[row][cj * 8] =
          *(const short8*)&Vbf[((size_t)(b * 2048 + s0 + row)) * 1024 + v0 + cj * 8];
    }
    __syncthreads();
    const int vrow = t >> 2, sq = t & 3;
#pragma unroll
    for (int hc = 0; hc < 2; ++hc) {
      float f[8];
#pragma unroll
      for (int e = 0; e < 8; ++e) {
        int p = sq * 16 + hc * 8 + e;
        int s = (p & 3) * 16 + (p >> 2);
        short sh = tile[s][vrow];
        f[e] = __bfloat162float(*(bf16*)&sh);
      }
      uint2 packed;
      packed.x = (unsigned int)pk4_fp8(f[0], f[1], f[2], f[3]);
      packed.y = (unsigned int)pk4_fp8(f[4], f[5], f[6], f[7]);
      *(uint2*)&Vt8[((size_t)(b * 1024 + v0 + vrow)) * 2048 + s0 + sq * 16 + hc * 8] = packed;
    }
  }
}

__global__ __launch_bounds__(256) void pv_gemm(const unsigned char* __restrict__ S8,
                                               const unsigned char* __restrict__ Vt8,
                                               const bf16* __restrict__ Vbf,
                                               const float* __restrict__ l,
                                               float* __restrict__ out) {
  __shared__ __align__(16) char lds[32768];
  const int id = blockIdx.x;
  const int r = id & 7, g = id >> 3;
  const int b = g >> 4;
  const int rem = g & 15;
  const int ty = r * 2 + (rem & 1);
  const int tx = rem >> 1;

  floatx4 acc[4][4];
  gemm_core_f8(S8 + (size_t)b * 2048 * 2048 + (size_t)ty * 128 * 2048,
               Vt8 + (size_t)b * 1024 * 2048 + (size_t)tx * 128 * 2048, 2048,
               (unsigned char*)lds, (unsigned char*)(lds + 16384), acc);

  const int tid = threadIdx.x, w = tid >> 6, lane = tid & 63;
  const int subM = (w >> 1) * 64, subN = (w & 1) * 64;
  const int fr = lane & 15, fq = lane >> 4;
  const int rowBase = ty * 128 + subM;
  const int colBase = tx * 128 + subN;
  const float* lb = l + (size_t)b * 2048;
#pragma unroll
  for (int i = 0; i < 4; ++i)
#pragma unroll
    for (int rr = 0; rr < 4; ++rr) {
      int row = rowBase + i * 16 + fq * 4 + rr;
      float inv = 1.0f / lb[row];
#pragma unroll
      for (int j = 0; j < 4; ++j) {
        int col = colBase + j * 16 + fr;
        size_t oi = ((size_t)b * 2048 + row) * 1024 + col;
        out[oi] = acc[i][j][rr] * inv + __bfloat162float(Vbf[oi]);
      }
    }
}

__global__ void cast_all(const float* __restrict__ x, const float* __restrict__ wq,
                         const float* __restrict__ wk, const float* __restrict__ wv,
                         bf16* __restrict__ Xbf, unsigned char* __restrict__ X8,
                         unsigned char* __restrict__ Wq8, unsigned char* __restrict__ Wk8,
                         bf16* __restrict__ Wvbf, float* __restrict__ l) {
  const int blk = blockIdx.x;
  const int t = threadIdx.x;
  if (blk < 8192) {
    int i = blk * 256 + t;
    float4 f = ((const float4*)x)[i];
    bf16 tmp[4] = {__float2bfloat16(f.x), __float2bfloat16(f.y),
                   __float2bfloat16(f.z), __float2bfloat16(f.w)};
    ((ushort4*)Xbf)[i] = *(const ushort4*)tmp;
    ((unsigned int*)X8)[i] = (unsigned int)pk4_fp8(f.x, f.y, f.z, f.w);
  } else if (blk < 10240) {
    const float* src = (blk < 9216) ? wq : wk;
    unsigned char* dst = (blk < 9216) ? Wq8 : Wk8;
    int i = ((blk - 8192) & 1023) * 256 + t;
    float4 f = ((const float4*)src)[i];
    ((unsigned int*)dst)[i] = (unsigned int)pk4_fp8(f.x, f.y, f.z, f.w);
  } else if (blk < 11264) {
    int i = (blk - 10240) * 256 + t;
    float4 f = ((const float4*)wv)[i];
    bf16 tmp[4] = {__float2bfloat16(f.x), __float2bfloat16(f.y),
                   __float2bfloat16(f.z), __float2bfloat16(f.w)};
    ((ushort4*)Wvbf)[i] = *(const ushort4*)tmp;
  } else {
    int i = (blk - 11264) * 256 + t;
    ((float4*)l)[i] = make_float4(0.f, 0.f, 0.f, 0.f);
  }
}

extern "C" void kernel_launch(void* const* d_in, const int* in_sizes, int n_in,
                              void* d_out, int out_size, void* d_ws, size_t ws_size,
                              hipStream_t stream) {
  const float* x  = (const float*)d_in[0];
  const float* Wq = (const float*)d_in[1];
  const float* Wk = (const float*)d_in[2];
  const float* Wv = (const float*)d_in[3];
  float* out = (float*)d_out;

  char* ws = (char*)d_ws;
  bf16* Xbf = (bf16*)ws;                   ws += (size_t)8192 * 1024 * 2;   // 16 MB
  unsigned char* X8 = (unsigned char*)ws;  ws += (size_t)8192 * 1024;       // 8 MB
  unsigned char* Wq8 = (unsigned char*)ws; ws += (size_t)1024 * 1024;       // 1 MB
  unsigned char* Wk8 = (unsigned char*)ws; ws += (size_t)1024 * 1024;       // 1 MB
  bf16* Wvbf = (bf16*)ws;                  ws += (size_t)1024 * 1024 * 2;   // 2 MB
  bf16* Vbf = (bf16*)ws;                   ws += (size_t)8192 * 1024 * 2;   // 16 MB
  unsigned char* Qf8 = (unsigned char*)ws; ws += (size_t)8192 * 1024;       // 8 MB
  unsigned char* Kf8 = (unsigned char*)ws; ws += (size_t)8192 * 1024;       // 8 MB
  unsigned char* S8  = (unsigned char*)ws; ws += (size_t)4 * 2048 * 2048;   // 16 MB
  unsigned char* Vt8 = (unsigned char*)ws; ws += (size_t)4 * 1024 * 2048;   // 8 MB
  float* l = (float*)ws;                   ws += (size_t)8192 * 4;

  // Deterministic host-side occupancy check (capture-safe): only use the
  // cooperative path if 512 blocks are guaranteed co-resident.
  int nb = 0;
  hipError_t qerr = hipOccupancyMaxActiveBlocksPerMultiprocessor(&nb, fused_all, 256, 0);
  if (qerr == hipSuccess && nb >= 2) {
    const float *xa = x, *wqa = Wq, *wka = Wk, *wva = Wv;
    void* args[] = {&xa, &wqa, &wka, &wva, &Xbf, &X8, &Wq8, &Wk8, &Wvbf, &Vbf,
                    &Qf8, &Kf8, &S8, &Vt8, &l, &out};
    hipError_t lerr = hipLaunchCooperativeKernel((const void*)fused_all, dim3(512),
                                                 dim3(256), args, 0, stream);
    if (lerr == hipSuccess) return;
  }
  // Fallback: proven R7 4-kernel path.
  cast_all<<<11272, 256, 0, stream>>>(x, Wq, Wk, Wv, Xbf, X8, Wq8, Wk8, Wvbf, l);
  proj_gemm<<<1024, 256, 0, stream>>>(Xbf, Wvbf, Vbf, X8, Wq8, Wk8, Qf8, Kf8);
  mid_kernel<<<2560, 256, 0, stream>>>(Qf8, Kf8, S8, l, Vbf, Vt8);
  pv_gemm<<<512, 256, 0, stream>>>(S8, Vt8, Vbf, l, out);
}